// Round 1
// baseline (1083.890 us; speedup 1.0000x reference)
//
#include <hip/hip_runtime.h>
#include <hip/hip_bf16.h>
#include <math.h>

typedef __bf16 bf16;
typedef __attribute__((ext_vector_type(8))) __bf16 bf16x8;
typedef __attribute__((ext_vector_type(4))) float f32x4;

#define GLL(gp, lp) __builtin_amdgcn_global_load_lds( \
    (const __attribute__((address_space(1))) unsigned int*)(gp), \
    (__attribute__((address_space(3))) unsigned int*)(lp), 16, 0, 0)

// ---------------------------------------------------------------------------
// Sizes: B=4, H=W=128 (n=16384/batch, 65536 rows total), C=512, HEADS=8, D=64
// ---------------------------------------------------------------------------

__device__ __forceinline__ bf16x8 cvt8(float4 a, float4 b) {
  bf16x8 o;
  o[0] = (bf16)a.x; o[1] = (bf16)a.y; o[2] = (bf16)a.z; o[3] = (bf16)a.w;
  o[4] = (bf16)b.x; o[5] = (bf16)b.y; o[6] = (bf16)b.z; o[7] = (bf16)b.w;
  return o;
}

// K0: x fp32 -> bf16; Wq|Wk|Wv fp32 -> concatenated bf16 (1536x512, N-major,
// K contiguous); zero attn accumulator + sumsq accumulators (ws is poisoned).
__global__ __launch_bounds__(256) void prep_kernel(
    const float* __restrict__ x, const float* __restrict__ Wq,
    const float* __restrict__ Wk, const float* __restrict__ Wv,
    bf16* __restrict__ xb, bf16* __restrict__ wqkv,
    float* __restrict__ zattn, float* __restrict__ ssq, float* __restrict__ ssk)
{
  const long XG = 33554432L / 8;   // x groups of 8
  const long WG = 262144L / 8;     // per-weight groups of 8
  long i = (long)blockIdx.x * 256 + threadIdx.x;
  if (i < XG) {
    const float4* xp = (const float4*)x;
    float4 a = xp[i * 2], b = xp[i * 2 + 1];
    *(bf16x8*)(xb + i * 8) = cvt8(a, b);
  } else if (i < XG + 3 * WG) {
    long j = i - XG;
    int w = (int)(j / WG);
    long r = j % WG;
    const float* src = (w == 0) ? Wq : ((w == 1) ? Wk : Wv);
    const float4* sp = (const float4*)src;
    float4 a = sp[r * 2], b = sp[r * 2 + 1];
    *(bf16x8*)(wqkv + (long)w * 262144 + r * 8) = cvt8(a, b);
  } else {
    long j = (i - XG - 3 * WG) * 8;   // float index into zero regions
    float4 z = make_float4(0.f, 0.f, 0.f, 0.f);
    if (j < 131072) {                 // attn accumulator 4*8*64*64
      *(float4*)(zattn + j) = z; *(float4*)(zattn + j + 4) = z;
    } else if (j < 133120) {          // sumsq_q 4*512
      long r = j - 131072; *(float4*)(ssq + r) = z; *(float4*)(ssq + r + 4) = z;
    } else {                          // sumsq_k 4*512
      long r = j - 133120; *(float4*)(ssk + r) = z; *(float4*)(ssk + r + 4) = z;
    }
  }
}

// ---------------------------------------------------------------------------
// m97-style bf16 NT-GEMM mainloop: A (Mx512 row-major), B (Nx512 row-major =
// B^T), 128x128 tile, BK=32, 256 threads = 4 waves each computing a 64x64
// quadrant as 4x4 MFMA 16x16x32 fragments. global_load_lds width=16 staging.
// ---------------------------------------------------------------------------
__device__ __forceinline__ void gemm_tile_mainloop(
    const bf16* __restrict__ A, const bf16* __restrict__ B,
    int m0, int n0, bf16* As, bf16* Bs, f32x4 acc[4][4])
{
  int tid = threadIdx.x;
  int lane = tid & 63, wave = tid >> 6;
  int wy = wave >> 1, wx = wave & 1;
  const bf16* ag = A + ((size_t)(m0 + (tid >> 2)) << 9) + (tid & 3) * 8;
  const bf16* bg = B + ((size_t)(n0 + (tid >> 2)) << 9) + (tid & 3) * 8;
  int mloc = lane & 15;
  int krow = (lane >> 4) * 8;
  // LDS chunk bases (wave-uniform): issue i covers chunks [i*256 + wave*64, +64)
  bf16* lA0 = As + wave * 512;
  bf16* lA1 = As + 2048 + wave * 512;
  bf16* lB0 = Bs + wave * 512;
  bf16* lB1 = Bs + 2048 + wave * 512;

  for (int k0 = 0; k0 < 512; k0 += 32) {
    GLL(ag + k0, lA0);
    GLL(ag + k0 + ((size_t)64 << 9), lA1);
    GLL(bg + k0, lB0);
    GLL(bg + k0 + ((size_t)64 << 9), lB1);
    __syncthreads();
    bf16x8 af[4], bfr[4];
#pragma unroll
    for (int tt = 0; tt < 4; tt++) {
      af[tt]  = *(const bf16x8*)&As[(wy * 64 + tt * 16 + mloc) * 32 + krow];
      bfr[tt] = *(const bf16x8*)&Bs[(wx * 64 + tt * 16 + mloc) * 32 + krow];
    }
#pragma unroll
    for (int ty = 0; ty < 4; ty++)
#pragma unroll
      for (int tx = 0; tx < 4; tx++)
        acc[ty][tx] = __builtin_amdgcn_mfma_f32_16x16x32_bf16(
            af[ty], bfr[tx], acc[ty][tx], 0, 0, 0);
    __syncthreads();
  }
}

// K1: QKV projection. C cols [0,512)=q, [512,1024)=k, [1024,1536)=v (v scaled
// by illu). Outputs bf16 row-major (65536 x 512) each.
__global__ __launch_bounds__(256) void gemm_qkv_kernel(
    const bf16* __restrict__ xb, const bf16* __restrict__ wqkv,
    const float* __restrict__ illu,
    bf16* __restrict__ qb, bf16* __restrict__ kb, bf16* __restrict__ vb)
{
  __shared__ __align__(16) bf16 As[4096];
  __shared__ __align__(16) bf16 Bs[4096];
  int bid = blockIdx.x;
  int mt = bid / 12, nt = bid % 12;
  int m0 = mt * 128, n0 = nt * 128;
  f32x4 acc[4][4] = {};
  gemm_tile_mainloop(xb, wqkv, m0, n0, As, Bs, acc);

  int tid = threadIdx.x, lane = tid & 63, wave = tid >> 6;
  int wy = wave >> 1, wx = wave & 1;
  int r0 = m0 + wy * 64 + ((lane >> 4) << 2);
  int c0 = n0 + wx * 64 + (lane & 15);
  int region = n0 >> 9;   // tile never crosses a 512-col boundary
#pragma unroll
  for (int ty = 0; ty < 4; ty++) {
#pragma unroll
    for (int tx = 0; tx < 4; tx++) {
      int gc = c0 + tx * 16;
      int lc = gc & 511;
#pragma unroll
      for (int r = 0; r < 4; r++) {
        int grow = r0 + ty * 16 + r;
        size_t idx = ((size_t)grow << 9) + lc;
        float v = acc[ty][tx][r];
        if (region == 0)      qb[idx] = (bf16)v;
        else if (region == 1) kb[idx] = (bf16)v;
        else                  vb[idx] = (bf16)(v * illu[idx]);
      }
    }
  }
}

// K2: per-(batch, column) sum of squares of q / k (for the l2norm over n).
__global__ __launch_bounds__(256) void colsumsq_kernel(
    const bf16* __restrict__ qb, const bf16* __restrict__ kb,
    float* __restrict__ ssq, float* __restrict__ ssk)
{
  __shared__ float red[4][512];
  const bf16* src = blockIdx.y ? kb : qb;
  float* dst = blockIdx.y ? ssk : ssq;
  int chunk = blockIdx.x;          // 512-row chunk; never crosses a batch
  int t = threadIdx.x;
  int cg = (t & 63) * 8, rs = t >> 6;
  float a[8] = {0, 0, 0, 0, 0, 0, 0, 0};
  size_t base = (size_t)chunk * 512 * 512;
  for (int r = rs; r < 512; r += 4) {
    bf16x8 v = *(const bf16x8*)(src + base + ((size_t)r << 9) + cg);
#pragma unroll
    for (int i = 0; i < 8; i++) { float f = (float)v[i]; a[i] += f * f; }
  }
#pragma unroll
  for (int i = 0; i < 8; i++) red[rs][cg + i] = a[i];
  __syncthreads();
  if (t < 64) {
    int batch = chunk >> 5;
#pragma unroll
    for (int i = 0; i < 8; i++) {
      int c = t * 8 + i;
      float s2 = red[0][c] + red[1][c] + red[2][c] + red[3][c];
      atomicAdd(dst + batch * 512 + c, s2);
    }
  }
}

// K3: S[b,h,d,e] = sum_n k[b,n,h*64+d] * q[b,n,h*64+e]  (unnormalized).
// grid (32 bh, 16 n-splits); block computes full 64x64, atomicAdd partials.
__global__ __launch_bounds__(256) void attn_dots_kernel(
    const bf16* __restrict__ qb, const bf16* __restrict__ kb,
    float* __restrict__ attn)
{
  __shared__ __align__(16) float ks[32 * 68];
  __shared__ __align__(16) float qs[32 * 68];
  int bh = blockIdx.x, sp = blockIdx.y;
  int b = bh >> 3, h = bh & 7;
  size_t hb = ((size_t)b << 23) + (size_t)h * 64;
  const bf16* qp = qb + hb;
  const bf16* kp = kb + hb;
  int t = threadIdx.x;
  int srow = t >> 3, scg = (t & 7) * 8;
  int d0 = (t & 15) * 4, e0 = (t >> 4) * 4;
  float acc[16] = {0};
  int nb = sp * 1024;
  for (int c = 0; c < 1024; c += 32) {
    size_t off = ((size_t)(nb + c + srow) << 9) + scg;
    bf16x8 kv = *(const bf16x8*)(kp + off);
    bf16x8 qv = *(const bf16x8*)(qp + off);
    __syncthreads();   // previous chunk's readers done
    float* kd = &ks[srow * 68 + scg];
    float* qd = &qs[srow * 68 + scg];
#pragma unroll
    for (int i = 0; i < 8; i++) { kd[i] = (float)kv[i]; qd[i] = (float)qv[i]; }
    __syncthreads();
#pragma unroll 8
    for (int n = 0; n < 32; n++) {
      float4 kr = *(const float4*)&ks[n * 68 + d0];
      float4 qr = *(const float4*)&qs[n * 68 + e0];
      acc[0]  += kr.x * qr.x; acc[1]  += kr.x * qr.y; acc[2]  += kr.x * qr.z; acc[3]  += kr.x * qr.w;
      acc[4]  += kr.y * qr.x; acc[5]  += kr.y * qr.y; acc[6]  += kr.y * qr.z; acc[7]  += kr.y * qr.w;
      acc[8]  += kr.z * qr.x; acc[9]  += kr.z * qr.y; acc[10] += kr.z * qr.z; acc[11] += kr.z * qr.w;
      acc[12] += kr.w * qr.x; acc[13] += kr.w * qr.y; acc[14] += kr.w * qr.z; acc[15] += kr.w * qr.w;
    }
  }
  float* ap = attn + ((size_t)bh << 12);
#pragma unroll
  for (int i = 0; i < 4; i++)
#pragma unroll
    for (int j = 0; j < 4; j++)
      atomicAdd(&ap[(d0 + i) * 64 + (e0 + j)], acc[i * 4 + j]);
}

// K4a: logits = S * rescale[h] / (nk[d] * nq[e]); softmax over e. In place.
__global__ __launch_bounds__(64) void softmax_kernel(
    float* __restrict__ attn, const float* __restrict__ ssq,
    const float* __restrict__ ssk, const float* __restrict__ rescale)
{
  int bh = blockIdx.x;
  int b = bh >> 3, h = bh & 7;
  int e = threadIdx.x;
  float nq = fmaxf(sqrtf(ssq[b * 512 + h * 64 + e]), 1e-12f);
  float rs = rescale[h];
  float* ap = attn + ((size_t)bh << 12);
  for (int d = 0; d < 64; d++) {
    float nk = fmaxf(sqrtf(ssk[b * 512 + h * 64 + d]), 1e-12f);
    float v = ap[d * 64 + e] * rs / (nk * nq);
    float m = v;
    for (int o = 32; o > 0; o >>= 1) m = fmaxf(m, __shfl_xor(m, o));
    float ex = expf(v - m);
    float s = ex;
    for (int o = 32; o > 0; o >>= 1) s += __shfl_xor(s, o);
    ap[d * 64 + e] = ex / s;
  }
}

// K4b: W_effT[b][co][h*64+e] = sum_d attn[b,h,d,e] * Wp[co, h*64+d]  (bf16).
// (exact reassociation of xo@Wp^T; out_c = v @ W_eff + bp)
__global__ __launch_bounds__(256) void weff_kernel(
    const float* __restrict__ attn, const float* __restrict__ Wp,
    bf16* __restrict__ wefT)
{
  int cog = blockIdx.x, h = blockIdx.y, b = blockIdx.z;
  __shared__ float at[4096];   // [d][e]
  __shared__ float wp[4096];   // [co_l][d]
  int t = threadIdx.x;
  const float* ap = attn + ((size_t)(b * 8 + h) << 12);
  for (int i = t; i < 4096; i += 256) at[i] = ap[i];
  for (int i = t; i < 4096; i += 256) {
    int r = i >> 6, d = i & 63;
    wp[i] = Wp[((size_t)(cog * 64 + r) << 9) + h * 64 + d];
  }
  __syncthreads();
  int co_l = (t & 15) * 4, e_l = (t >> 4) * 4;
  float acc[16] = {0};
  for (int d = 0; d < 64; d++) {
    float w0 = wp[(co_l + 0) * 64 + d];
    float w1 = wp[(co_l + 1) * 64 + d];
    float w2 = wp[(co_l + 2) * 64 + d];
    float w3 = wp[(co_l + 3) * 64 + d];
    float4 av = *(const float4*)&at[d * 64 + e_l];
    acc[0]  += w0 * av.x; acc[1]  += w0 * av.y; acc[2]  += w0 * av.z; acc[3]  += w0 * av.w;
    acc[4]  += w1 * av.x; acc[5]  += w1 * av.y; acc[6]  += w1 * av.z; acc[7]  += w1 * av.w;
    acc[8]  += w2 * av.x; acc[9]  += w2 * av.y; acc[10] += w2 * av.z; acc[11] += w2 * av.w;
    acc[12] += w3 * av.x; acc[13] += w3 * av.y; acc[14] += w3 * av.z; acc[15] += w3 * av.w;
  }
#pragma unroll
  for (int i = 0; i < 4; i++)
#pragma unroll
    for (int j = 0; j < 4; j++)
      wefT[((size_t)b << 18) + ((size_t)(cog * 64 + co_l + i) << 9) + h * 64 + e_l + j] =
          (bf16)acc[i * 4 + j];
}

// K5: out_c = v @ W_eff[b] + bp  -> d_out (fp32). Same mainloop as K1.
__global__ __launch_bounds__(256) void gemm_out_kernel(
    const bf16* __restrict__ vb, const bf16* __restrict__ wefT,
    const float* __restrict__ bp, float* __restrict__ out)
{
  __shared__ __align__(16) bf16 As[4096];
  __shared__ __align__(16) bf16 Bs[4096];
  int b = blockIdx.y;
  int mt = blockIdx.x >> 2, nt = blockIdx.x & 3;
  int m0 = mt * 128, n0 = nt * 128;
  const bf16* A = vb + ((size_t)b << 23);
  const bf16* B = wefT + ((size_t)b << 18);
  f32x4 acc[4][4] = {};
  gemm_tile_mainloop(A, B, m0, n0, As, Bs, acc);

  int tid = threadIdx.x, lane = tid & 63, wave = tid >> 6;
  int wy = wave >> 1, wx = wave & 1;
  int r0 = (b << 14) + m0 + wy * 64 + ((lane >> 4) << 2);
  int c0 = n0 + wx * 64 + (lane & 15);
#pragma unroll
  for (int ty = 0; ty < 4; ty++) {
#pragma unroll
    for (int tx = 0; tx < 4; tx++) {
      int lc = c0 + tx * 16;
      float bias = bp[lc];
#pragma unroll
      for (int r = 0; r < 4; r++) {
        int grow = r0 + ty * 16 + r;
        out[((size_t)grow << 9) + lc] = acc[ty][tx][r] + bias;
      }
    }
  }
}

// K6: p = gelu_erf(dwconv3x3(v, pe1))  (NHWC, zero-pad SAME), bf16 out.
__global__ __launch_bounds__(256) void conv1_kernel(
    const bf16* __restrict__ vb, const float* __restrict__ pe1,
    bf16* __restrict__ pbuf)
{
  int b = blockIdx.y;
  int tile = blockIdx.x;
  int y0 = (tile >> 4) * 8, x0 = (tile & 15) * 8;
  int t = threadIdx.x;
  int cg = (t & 63) * 8, sp0 = t >> 6;
  float w[72];
#pragma unroll
  for (int i = 0; i < 8; i++)
#pragma unroll
    for (int k = 0; k < 9; k++)
      w[i * 9 + k] = pe1[(cg + i) * 9 + k];
  const bf16* vbase = vb + ((size_t)b << 23);
  bf16* pb = pbuf + ((size_t)b << 23);
  for (int s = sp0; s < 64; s += 4) {
    int y = y0 + (s >> 3), x = x0 + (s & 7);
    float a[8] = {0, 0, 0, 0, 0, 0, 0, 0};
#pragma unroll
    for (int ky = 0; ky < 3; ky++) {
      int yy = y + ky - 1;
      if (yy < 0 || yy >= 128) continue;
#pragma unroll
      for (int kx = 0; kx < 3; kx++) {
        int xx = x + kx - 1;
        if (xx < 0 || xx >= 128) continue;
        bf16x8 vv = *(const bf16x8*)&vbase[((size_t)(yy * 128 + xx) << 9) + cg];
#pragma unroll
        for (int i = 0; i < 8; i++) a[i] += (float)vv[i] * w[i * 9 + ky * 3 + kx];
      }
    }
    bf16x8 o;
#pragma unroll
    for (int i = 0; i < 8; i++) {
      float g = 0.5f * a[i] * (1.0f + erff(a[i] * 0.70710678118654752f));
      o[i] = (bf16)g;
    }
    *(bf16x8*)&pb[((size_t)(y * 128 + x) << 9) + cg] = o;
  }
}

// K7: out += dwconv3x3(p, pe2)   (read-modify-write fp32 d_out).
__global__ __launch_bounds__(256) void conv2_kernel(
    const bf16* __restrict__ pbuf, const float* __restrict__ pe2,
    float* __restrict__ out)
{
  int b = blockIdx.y;
  int tile = blockIdx.x;
  int y0 = (tile >> 4) * 8, x0 = (tile & 15) * 8;
  int t = threadIdx.x;
  int cg = (t & 63) * 8, sp0 = t >> 6;
  float w[72];
#pragma unroll
  for (int i = 0; i < 8; i++)
#pragma unroll
    for (int k = 0; k < 9; k++)
      w[i * 9 + k] = pe2[(cg + i) * 9 + k];
  const bf16* pb = pbuf + ((size_t)b << 23);
  float* ob = out + ((size_t)b << 23);
  for (int s = sp0; s < 64; s += 4) {
    int y = y0 + (s >> 3), x = x0 + (s & 7);
    float a[8] = {0, 0, 0, 0, 0, 0, 0, 0};
#pragma unroll
    for (int ky = 0; ky < 3; ky++) {
      int yy = y + ky - 1;
      if (yy < 0 || yy >= 128) continue;
#pragma unroll
      for (int kx = 0; kx < 3; kx++) {
        int xx = x + kx - 1;
        if (xx < 0 || xx >= 128) continue;
        bf16x8 vv = *(const bf16x8*)&pb[((size_t)(yy * 128 + xx) << 9) + cg];
#pragma unroll
        for (int i = 0; i < 8; i++) a[i] += (float)vv[i] * w[i * 9 + ky * 3 + kx];
      }
    }
    size_t oi = ((size_t)(y * 128 + x) << 9) + cg;
    float4 o0 = *(float4*)&ob[oi];
    float4 o1 = *(float4*)&ob[oi + 4];
    o0.x += a[0]; o0.y += a[1]; o0.z += a[2]; o0.w += a[3];
    o1.x += a[4]; o1.y += a[5]; o1.z += a[6]; o1.w += a[7];
    *(float4*)&ob[oi] = o0;
    *(float4*)&ob[oi + 4] = o1;
  }
}

extern "C" void kernel_launch(void* const* d_in, const int* in_sizes, int n_in,
                              void* d_out, int out_size, void* d_ws, size_t ws_size,
                              hipStream_t stream) {
  (void)in_sizes; (void)n_in; (void)out_size; (void)ws_size;
  const float* x       = (const float*)d_in[0];
  const float* illu    = (const float*)d_in[1];
  const float* Wq      = (const float*)d_in[2];
  const float* Wk      = (const float*)d_in[3];
  const float* Wv      = (const float*)d_in[4];
  const float* rescale = (const float*)d_in[5];
  const float* Wp      = (const float*)d_in[6];
  const float* bp      = (const float*)d_in[7];
  const float* pe1     = (const float*)d_in[8];
  const float* pe2     = (const float*)d_in[9];
  float* out = (float*)d_out;
  char* ws = (char*)d_ws;

  // workspace layout (bytes); total = 272,646,144
  bf16*  xb   = (bf16*)(ws);                      // 67,108,864  (reused as pbuf)
  bf16*  wqkv = (bf16*)(ws + 67108864);           //  1,572,864
  bf16*  qb   = (bf16*)(ws + 68681728);           // 67,108,864
  bf16*  kb   = (bf16*)(ws + 135790592);          // 67,108,864
  bf16*  vb   = (bf16*)(ws + 202899456);          // 67,108,864
  float* ssq  = (float*)(ws + 270008320);         //      8,192
  float* ssk  = (float*)(ws + 270016512);         //      8,192
  float* attn = (float*)(ws + 270024704);         //    524,288
  bf16*  wefT = (bf16*)(ws + 270548992);          //  2,097,152
  bf16*  pbuf = xb;                               // x dead after gemm_qkv

  prep_kernel<<<16834, 256, 0, stream>>>(x, Wq, Wk, Wv, xb, wqkv, attn, ssq, ssk);
  gemm_qkv_kernel<<<6144, 256, 0, stream>>>(xb, wqkv, illu, qb, kb, vb);
  colsumsq_kernel<<<dim3(128, 2), 256, 0, stream>>>(qb, kb, ssq, ssk);
  attn_dots_kernel<<<dim3(32, 16), 256, 0, stream>>>(qb, kb, attn);
  softmax_kernel<<<32, 64, 0, stream>>>(attn, ssq, ssk, rescale);
  weff_kernel<<<dim3(8, 8, 4), 256, 0, stream>>>(attn, Wp, wefT);
  gemm_out_kernel<<<dim3(512, 4), 256, 0, stream>>>(vb, wefT, bp, out);
  conv1_kernel<<<dim3(256, 4), 256, 0, stream>>>(vb, pe1, pbuf);
  conv2_kernel<<<dim3(256, 4), 256, 0, stream>>>(pbuf, pe2, out);
}

// Round 2
// 933.402 us; speedup vs baseline: 1.1612x; 1.1612x over previous
//
#include <hip/hip_runtime.h>
#include <hip/hip_bf16.h>
#include <math.h>

typedef __bf16 bf16;
typedef __attribute__((ext_vector_type(8))) __bf16 bf16x8;
typedef __attribute__((ext_vector_type(4))) float f32x4;

#define GLL(gp, lp) __builtin_amdgcn_global_load_lds( \
    (const __attribute__((address_space(1))) unsigned int*)(gp), \
    (__attribute__((address_space(3))) unsigned int*)(lp), 16, 0, 0)

// ---------------------------------------------------------------------------
// Sizes: B=4, H=W=128 (n=16384/batch, 65536 rows total), C=512, HEADS=8, D=64
// ---------------------------------------------------------------------------

__device__ __forceinline__ bf16x8 cvt8(float4 a, float4 b) {
  bf16x8 o;
  o[0] = (bf16)a.x; o[1] = (bf16)a.y; o[2] = (bf16)a.z; o[3] = (bf16)a.w;
  o[4] = (bf16)b.x; o[5] = (bf16)b.y; o[6] = (bf16)b.z; o[7] = (bf16)b.w;
  return o;
}

// K0: x fp32 -> bf16; Wq|Wk|Wv fp32 -> concatenated bf16 (1536x512, N-major,
// K contiguous); zero attn accumulator + sumsq accumulators (ws is poisoned).
__global__ __launch_bounds__(256) void prep_kernel(
    const float* __restrict__ x, const float* __restrict__ Wq,
    const float* __restrict__ Wk, const float* __restrict__ Wv,
    bf16* __restrict__ xb, bf16* __restrict__ wqkv,
    float* __restrict__ zattn, float* __restrict__ ssq, float* __restrict__ ssk)
{
  const long XG = 33554432L / 8;   // x groups of 8
  const long WG = 262144L / 8;     // per-weight groups of 8
  long i = (long)blockIdx.x * 256 + threadIdx.x;
  if (i < XG) {
    const float4* xp = (const float4*)x;
    float4 a = xp[i * 2], b = xp[i * 2 + 1];
    *(bf16x8*)(xb + i * 8) = cvt8(a, b);
  } else if (i < XG + 3 * WG) {
    long j = i - XG;
    int w = (int)(j / WG);
    long r = j % WG;
    const float* src = (w == 0) ? Wq : ((w == 1) ? Wk : Wv);
    const float4* sp = (const float4*)src;
    float4 a = sp[r * 2], b = sp[r * 2 + 1];
    *(bf16x8*)(wqkv + (long)w * 262144 + r * 8) = cvt8(a, b);
  } else {
    long j = (i - XG - 3 * WG) * 8;   // float index into zero regions
    float4 z = make_float4(0.f, 0.f, 0.f, 0.f);
    if (j < 131072) {                 // attn accumulator 4*8*64*64
      *(float4*)(zattn + j) = z; *(float4*)(zattn + j + 4) = z;
    } else if (j < 133120) {          // sumsq_q 4*512
      long r = j - 131072; *(float4*)(ssq + r) = z; *(float4*)(ssq + r + 4) = z;
    } else {                          // sumsq_k 4*512
      long r = j - 133120; *(float4*)(ssk + r) = z; *(float4*)(ssk + r + 4) = z;
    }
  }
}

// ---------------------------------------------------------------------------
// bf16 NT-GEMM mainloop v2: A (Mx512 rm), B (Nx512 rm = B^T), 128x128 tile,
// BK=64 (8 K-iters), 256 threads = 4 waves, each wave a 64x64 quadrant as
// 4x4 MFMA 16x16x32 frags x 2 k-halves. global_load_lds width=16 staging
// with XOR chunk swizzle applied on the GLOBAL address side (GLL's LDS dest
// is wave-base + lane*16, so the source address carries the permutation):
// LDS[row][slot] holds global chunk [row][slot ^ (row&7)] -> ds_read_b128
// fragment reads are bank-conflict-free (rows 0..7 cover all 32 banks).
// ---------------------------------------------------------------------------
__device__ __forceinline__ void gemm_tile_mainloop(
    const bf16* __restrict__ A, const bf16* __restrict__ B,
    int m0, int n0, bf16* As, bf16* Bs, f32x4 acc[4][4])
{
  int tid = threadIdx.x;
  int lane = tid & 63, wave = tid >> 6;
  int wy = wave >> 1, wx = wave & 1;
  // staging: chunk c = issue*256 + tid; row = c>>3 (0..127), slot = c&7.
  // issue adds 32 rows (low 3 bits of row unchanged -> same xor key).
  int srow = tid >> 3;                       // 0..31
  int scol = ((tid & 7) ^ (srow & 7)) * 8;   // swizzled global column
  const bf16* ag = A + ((size_t)(m0 + srow) << 9) + scol;
  const bf16* bg = B + ((size_t)(n0 + srow) << 9) + scol;
  bf16* lA = As + wave * 512;                // issue i adds 2048 (=4KB)
  bf16* lB = Bs + wave * 512;
  int mloc = lane & 15;
  int kq = lane >> 4;                        // quad -> k-chunk within half

  for (int k0 = 0; k0 < 512; k0 += 64) {
#pragma unroll
    for (int i = 0; i < 4; i++) {
      GLL(ag + k0 + i * 16384, lA + i * 2048);
      GLL(bg + k0 + i * 16384, lB + i * 2048);
    }
    __syncthreads();
#pragma unroll
    for (int kh = 0; kh < 2; kh++) {
      bf16x8 af[4], bfr[4];
      int logical = kh * 4 + kq;             // 16B chunk index in row
#pragma unroll
      for (int tt = 0; tt < 4; tt++) {
        int arow = wy * 64 + tt * 16 + mloc;
        af[tt] = *(const bf16x8*)&As[arow * 64 + (logical ^ (arow & 7)) * 8];
        int brow = wx * 64 + tt * 16 + mloc;
        bfr[tt] = *(const bf16x8*)&Bs[brow * 64 + (logical ^ (brow & 7)) * 8];
      }
#pragma unroll
      for (int ty = 0; ty < 4; ty++)
#pragma unroll
        for (int tx = 0; tx < 4; tx++)
          acc[ty][tx] = __builtin_amdgcn_mfma_f32_16x16x32_bf16(
              af[ty], bfr[tx], acc[ty][tx], 0, 0, 0);
    }
    __syncthreads();
  }
}

// K1: QKV projection. N-cols [0,512)=q, [512,1024)=k, [1024,1536)=v (v scaled
// by illu). Outputs bf16 row-major (65536 x 512). Fused: column sum-of-squares
// of fp32 q/k accumulators (for the l2norm over n) via shuffle + atomicAdd.
// XCD swizzle: the 12 nt-siblings of an mt run on one XCD -> A panel L2-hot.
__global__ __launch_bounds__(256) void gemm_qkv_kernel(
    const bf16* __restrict__ xb, const bf16* __restrict__ wqkv,
    const float* __restrict__ illu,
    bf16* __restrict__ qb, bf16* __restrict__ kb, bf16* __restrict__ vb,
    float* __restrict__ ssq, float* __restrict__ ssk)
{
  __shared__ __align__(16) bf16 As[8192];
  __shared__ __align__(16) bf16 Bs[8192];
  int bid = blockIdx.x;
  int xcd = bid & 7, s = bid >> 3;          // s in [0,768)
  int mt = xcd * 64 + s / 12, nt = s % 12;
  int m0 = mt * 128, n0 = nt * 128;
  f32x4 acc[4][4] = {};
  gemm_tile_mainloop(xb, wqkv, m0, n0, As, Bs, acc);

  int tid = threadIdx.x, lane = tid & 63, wave = tid >> 6;
  int wy = wave >> 1, wx = wave & 1;
  int r0 = m0 + wy * 64 + ((lane >> 4) << 2);
  int c0 = n0 + wx * 64 + (lane & 15);
  int region = n0 >> 9;   // tile never crosses a 512-col boundary
  if (region < 2) {
    bf16* outp = region ? kb : qb;
    float* dst = (region ? ssk : ssq) + (m0 >> 14) * 512;
#pragma unroll
    for (int tx = 0; tx < 4; tx++) {
      int lc = (c0 + tx * 16) & 511;
      float ss = 0.f;
#pragma unroll
      for (int ty = 0; ty < 4; ty++) {
#pragma unroll
        for (int r = 0; r < 4; r++) {
          float v = acc[ty][tx][r];
          ss += v * v;
          outp[((size_t)(r0 + ty * 16 + r) << 9) + lc] = (bf16)v;
        }
      }
      ss += __shfl_xor(ss, 16);
      ss += __shfl_xor(ss, 32);
      if ((lane >> 4) == 0) atomicAdd(dst + lc, ss);
    }
  } else {
#pragma unroll
    for (int tx = 0; tx < 4; tx++) {
      int lc = (c0 + tx * 16) & 511;
#pragma unroll
      for (int ty = 0; ty < 4; ty++) {
#pragma unroll
        for (int r = 0; r < 4; r++) {
          size_t idx = ((size_t)(r0 + ty * 16 + r) << 9) + lc;
          vb[idx] = (bf16)(acc[ty][tx][r] * illu[idx]);
        }
      }
    }
  }
}

// K3: S[b,h,d,e] = sum_n k[b,n,h*64+d] * q[b,n,h*64+e]  (unnormalized).
// grid (32 bh, 16 n-splits); block computes full 64x64, atomicAdd partials.
__global__ __launch_bounds__(256) void attn_dots_kernel(
    const bf16* __restrict__ qb, const bf16* __restrict__ kb,
    float* __restrict__ attn)
{
  __shared__ __align__(16) float ks[32 * 68];
  __shared__ __align__(16) float qs[32 * 68];
  int bh = blockIdx.x, sp = blockIdx.y;
  int b = bh >> 3, h = bh & 7;
  size_t hb = ((size_t)b << 23) + (size_t)h * 64;
  const bf16* qp = qb + hb;
  const bf16* kp = kb + hb;
  int t = threadIdx.x;
  int srow = t >> 3, scg = (t & 7) * 8;
  int d0 = (t & 15) * 4, e0 = (t >> 4) * 4;
  float acc[16] = {0};
  int nb = sp * 1024;
  for (int c = 0; c < 1024; c += 32) {
    size_t off = ((size_t)(nb + c + srow) << 9) + scg;
    bf16x8 kv = *(const bf16x8*)(kp + off);
    bf16x8 qv = *(const bf16x8*)(qp + off);
    __syncthreads();   // previous chunk's readers done
    float* kd = &ks[srow * 68 + scg];
    float* qd = &qs[srow * 68 + scg];
#pragma unroll
    for (int i = 0; i < 8; i++) { kd[i] = (float)kv[i]; qd[i] = (float)qv[i]; }
    __syncthreads();
#pragma unroll 8
    for (int n = 0; n < 32; n++) {
      float4 kr = *(const float4*)&ks[n * 68 + d0];
      float4 qr = *(const float4*)&qs[n * 68 + e0];
      acc[0]  += kr.x * qr.x; acc[1]  += kr.x * qr.y; acc[2]  += kr.x * qr.z; acc[3]  += kr.x * qr.w;
      acc[4]  += kr.y * qr.x; acc[5]  += kr.y * qr.y; acc[6]  += kr.y * qr.z; acc[7]  += kr.y * qr.w;
      acc[8]  += kr.z * qr.x; acc[9]  += kr.z * qr.y; acc[10] += kr.z * qr.z; acc[11] += kr.z * qr.w;
      acc[12] += kr.w * qr.x; acc[13] += kr.w * qr.y; acc[14] += kr.w * qr.z; acc[15] += kr.w * qr.w;
    }
  }
  float* ap = attn + ((size_t)bh << 12);
#pragma unroll
  for (int i = 0; i < 4; i++)
#pragma unroll
    for (int j = 0; j < 4; j++)
      atomicAdd(&ap[(d0 + i) * 64 + (e0 + j)], acc[i * 4 + j]);
}

// K4a: logits = S * rescale[h] / (nk[d] * nq[e]); softmax over e. In place.
__global__ __launch_bounds__(64) void softmax_kernel(
    float* __restrict__ attn, const float* __restrict__ ssq,
    const float* __restrict__ ssk, const float* __restrict__ rescale)
{
  int bh = blockIdx.x;
  int b = bh >> 3, h = bh & 7;
  int e = threadIdx.x;
  float nq = fmaxf(sqrtf(ssq[b * 512 + h * 64 + e]), 1e-12f);
  float rs = rescale[h];
  float* ap = attn + ((size_t)bh << 12);
  for (int d = 0; d < 64; d++) {
    float nk = fmaxf(sqrtf(ssk[b * 512 + h * 64 + d]), 1e-12f);
    float v = ap[d * 64 + e] * rs / (nk * nq);
    float m = v;
    for (int o = 32; o > 0; o >>= 1) m = fmaxf(m, __shfl_xor(m, o));
    float ex = expf(v - m);
    float s = ex;
    for (int o = 32; o > 0; o >>= 1) s += __shfl_xor(s, o);
    ap[d * 64 + e] = ex / s;
  }
}

// K4b: W_effT[b][co][h*64+e] = sum_d attn[b,h,d,e] * Wp[co, h*64+d]  (bf16).
// (exact reassociation of xo@Wp^T; out_c = v @ W_eff + bp)
__global__ __launch_bounds__(256) void weff_kernel(
    const float* __restrict__ attn, const float* __restrict__ Wp,
    bf16* __restrict__ wefT)
{
  int cog = blockIdx.x, h = blockIdx.y, b = blockIdx.z;
  __shared__ float at[4096];   // [d][e]
  __shared__ float wp[4096];   // [co_l][d]
  int t = threadIdx.x;
  const float* ap = attn + ((size_t)(b * 8 + h) << 12);
  for (int i = t; i < 4096; i += 256) at[i] = ap[i];
  for (int i = t; i < 4096; i += 256) {
    int r = i >> 6, d = i & 63;
    wp[i] = Wp[((size_t)(cog * 64 + r) << 9) + h * 64 + d];
  }
  __syncthreads();
  int co_l = (t & 15) * 4, e_l = (t >> 4) * 4;
  float acc[16] = {0};
  for (int d = 0; d < 64; d++) {
    float w0 = wp[(co_l + 0) * 64 + d];
    float w1 = wp[(co_l + 1) * 64 + d];
    float w2 = wp[(co_l + 2) * 64 + d];
    float w3 = wp[(co_l + 3) * 64 + d];
    float4 av = *(const float4*)&at[d * 64 + e_l];
    acc[0]  += w0 * av.x; acc[1]  += w0 * av.y; acc[2]  += w0 * av.z; acc[3]  += w0 * av.w;
    acc[4]  += w1 * av.x; acc[5]  += w1 * av.y; acc[6]  += w1 * av.z; acc[7]  += w1 * av.w;
    acc[8]  += w2 * av.x; acc[9]  += w2 * av.y; acc[10] += w2 * av.z; acc[11] += w2 * av.w;
    acc[12] += w3 * av.x; acc[13] += w3 * av.y; acc[14] += w3 * av.z; acc[15] += w3 * av.w;
  }
#pragma unroll
  for (int i = 0; i < 4; i++)
#pragma unroll
    for (int j = 0; j < 4; j++)
      wefT[((size_t)b << 18) + ((size_t)(cog * 64 + co_l + i) << 9) + h * 64 + e_l + j] =
          (bf16)acc[i * 4 + j];
}

// K5: out_c = v @ W_eff[b] + bp  -> d_out (fp32). Same mainloop as K1.
// XCD swizzle: the 4 nt-siblings of an mt share one XCD.
__global__ __launch_bounds__(256) void gemm_out_kernel(
    const bf16* __restrict__ vb, const bf16* __restrict__ wefT,
    const float* __restrict__ bp, float* __restrict__ out)
{
  __shared__ __align__(16) bf16 As[8192];
  __shared__ __align__(16) bf16 Bs[8192];
  int b = blockIdx.y;
  int bid = blockIdx.x;
  int xcd = bid & 7, s = bid >> 3;          // s in [0,64)
  int mt = xcd * 16 + (s >> 2), nt = s & 3;
  int m0 = mt * 128, n0 = nt * 128;
  const bf16* A = vb + ((size_t)b << 23);
  const bf16* B = wefT + ((size_t)b << 18);
  f32x4 acc[4][4] = {};
  gemm_tile_mainloop(A, B, m0, n0, As, Bs, acc);

  int tid = threadIdx.x, lane = tid & 63, wave = tid >> 6;
  int wy = wave >> 1, wx = wave & 1;
  int r0 = (b << 14) + m0 + wy * 64 + ((lane >> 4) << 2);
  int c0 = n0 + wx * 64 + (lane & 15);
#pragma unroll
  for (int ty = 0; ty < 4; ty++) {
#pragma unroll
    for (int tx = 0; tx < 4; tx++) {
      int lc = c0 + tx * 16;
      float bias = bp[lc];
#pragma unroll
      for (int r = 0; r < 4; r++) {
        int grow = r0 + ty * 16 + r;
        out[((size_t)grow << 9) + lc] = acc[ty][tx][r] + bias;
      }
    }
  }
}

// K6: p = gelu_erf(dwconv3x3(v, pe1))  (NHWC, zero-pad SAME), bf16 out.
__global__ __launch_bounds__(256) void conv1_kernel(
    const bf16* __restrict__ vb, const float* __restrict__ pe1,
    bf16* __restrict__ pbuf)
{
  int b = blockIdx.y;
  int tile = blockIdx.x;
  int y0 = (tile >> 4) * 8, x0 = (tile & 15) * 8;
  int t = threadIdx.x;
  int cg = (t & 63) * 8, sp0 = t >> 6;
  float w[72];
#pragma unroll
  for (int i = 0; i < 8; i++)
#pragma unroll
    for (int k = 0; k < 9; k++)
      w[i * 9 + k] = pe1[(cg + i) * 9 + k];
  const bf16* vbase = vb + ((size_t)b << 23);
  bf16* pb = pbuf + ((size_t)b << 23);
  for (int s = sp0; s < 64; s += 4) {
    int y = y0 + (s >> 3), x = x0 + (s & 7);
    float a[8] = {0, 0, 0, 0, 0, 0, 0, 0};
#pragma unroll
    for (int ky = 0; ky < 3; ky++) {
      int yy = y + ky - 1;
      if (yy < 0 || yy >= 128) continue;
#pragma unroll
      for (int kx = 0; kx < 3; kx++) {
        int xx = x + kx - 1;
        if (xx < 0 || xx >= 128) continue;
        bf16x8 vv = *(const bf16x8*)&vbase[((size_t)(yy * 128 + xx) << 9) + cg];
#pragma unroll
        for (int i = 0; i < 8; i++) a[i] += (float)vv[i] * w[i * 9 + ky * 3 + kx];
      }
    }
    bf16x8 o;
#pragma unroll
    for (int i = 0; i < 8; i++) {
      float g = 0.5f * a[i] * (1.0f + erff(a[i] * 0.70710678118654752f));
      o[i] = (bf16)g;
    }
    *(bf16x8*)&pb[((size_t)(y * 128 + x) << 9) + cg] = o;
  }
}

// K7: out += dwconv3x3(p, pe2)   (read-modify-write fp32 d_out).
__global__ __launch_bounds__(256) void conv2_kernel(
    const bf16* __restrict__ pbuf, const float* __restrict__ pe2,
    float* __restrict__ out)
{
  int b = blockIdx.y;
  int tile = blockIdx.x;
  int y0 = (tile >> 4) * 8, x0 = (tile & 15) * 8;
  int t = threadIdx.x;
  int cg = (t & 63) * 8, sp0 = t >> 6;
  float w[72];
#pragma unroll
  for (int i = 0; i < 8; i++)
#pragma unroll
    for (int k = 0; k < 9; k++)
      w[i * 9 + k] = pe2[(cg + i) * 9 + k];
  const bf16* pb = pbuf + ((size_t)b << 23);
  float* ob = out + ((size_t)b << 23);
  for (int s = sp0; s < 64; s += 4) {
    int y = y0 + (s >> 3), x = x0 + (s & 7);
    float a[8] = {0, 0, 0, 0, 0, 0, 0, 0};
#pragma unroll
    for (int ky = 0; ky < 3; ky++) {
      int yy = y + ky - 1;
      if (yy < 0 || yy >= 128) continue;
#pragma unroll
      for (int kx = 0; kx < 3; kx++) {
        int xx = x + kx - 1;
        if (xx < 0 || xx >= 128) continue;
        bf16x8 vv = *(const bf16x8*)&pb[((size_t)(yy * 128 + xx) << 9) + cg];
#pragma unroll
        for (int i = 0; i < 8; i++) a[i] += (float)vv[i] * w[i * 9 + ky * 3 + kx];
      }
    }
    size_t oi = ((size_t)(y * 128 + x) << 9) + cg;
    float4 o0 = *(float4*)&ob[oi];
    float4 o1 = *(float4*)&ob[oi + 4];
    o0.x += a[0]; o0.y += a[1]; o0.z += a[2]; o0.w += a[3];
    o1.x += a[4]; o1.y += a[5]; o1.z += a[6]; o1.w += a[7];
    *(float4*)&ob[oi] = o0;
    *(float4*)&ob[oi + 4] = o1;
  }
}

extern "C" void kernel_launch(void* const* d_in, const int* in_sizes, int n_in,
                              void* d_out, int out_size, void* d_ws, size_t ws_size,
                              hipStream_t stream) {
  (void)in_sizes; (void)n_in; (void)out_size; (void)ws_size;
  const float* x       = (const float*)d_in[0];
  const float* illu    = (const float*)d_in[1];
  const float* Wq      = (const float*)d_in[2];
  const float* Wk      = (const float*)d_in[3];
  const float* Wv      = (const float*)d_in[4];
  const float* rescale = (const float*)d_in[5];
  const float* Wp      = (const float*)d_in[6];
  const float* bp      = (const float*)d_in[7];
  const float* pe1     = (const float*)d_in[8];
  const float* pe2     = (const float*)d_in[9];
  float* out = (float*)d_out;
  char* ws = (char*)d_ws;

  // workspace layout (bytes); total = 272,646,144
  bf16*  xb   = (bf16*)(ws);                      // 67,108,864  (reused as pbuf)
  bf16*  wqkv = (bf16*)(ws + 67108864);           //  1,572,864
  bf16*  qb   = (bf16*)(ws + 68681728);           // 67,108,864
  bf16*  kb   = (bf16*)(ws + 135790592);          // 67,108,864
  bf16*  vb   = (bf16*)(ws + 202899456);          // 67,108,864
  float* ssq  = (float*)(ws + 270008320);         //      8,192
  float* ssk  = (float*)(ws + 270016512);         //      8,192
  float* attn = (float*)(ws + 270024704);         //    524,288
  bf16*  wefT = (bf16*)(ws + 270548992);          //  2,097,152
  bf16*  pbuf = xb;                               // x dead after gemm_qkv

  prep_kernel<<<16834, 256, 0, stream>>>(x, Wq, Wk, Wv, xb, wqkv, attn, ssq, ssk);
  gemm_qkv_kernel<<<6144, 256, 0, stream>>>(xb, wqkv, illu, qb, kb, vb, ssq, ssk);
  attn_dots_kernel<<<dim3(32, 16), 256, 0, stream>>>(qb, kb, attn);
  softmax_kernel<<<32, 64, 0, stream>>>(attn, ssq, ssk, rescale);
  weff_kernel<<<dim3(8, 8, 4), 256, 0, stream>>>(attn, Wp, wefT);
  gemm_out_kernel<<<dim3(512, 4), 256, 0, stream>>>(vb, wefT, bp, out);
  conv1_kernel<<<dim3(256, 4), 256, 0, stream>>>(vb, pe1, pbuf);
  conv2_kernel<<<dim3(256, 4), 256, 0, stream>>>(pbuf, pe2, out);
}